// Round 6
// baseline (468.016 us; speedup 1.0000x reference)
//
#include <hip/hip_runtime.h>
#include <hip/hip_bf16.h>
#include <cstdint>

// ---------------------------------------------------------------------------
// RoPE Multi-Head Self-Attention, MI355X (gfx950)
// B=32, S=577, E=768, H=12, Dh=64.
// DTYPES (r5 forensics, contract-confirmed): inputs fp32, OUTPUT fp32.
// (r3-r5 bit-identical 0.104 error == signature of bf16 stores read as fp32;
//  harness quantizes only the REFERENCE to bf16 for thresholding.)
// Internally: bf16 MFMA, fp32 accumulate; qkv workspace bf16.
// Pipeline: [K1] qkv = bf16(x) @ bf16(w_qkv)^T   -> ws  (rows [q|k|v])
//           [K2] RoPE in-place on q,k patch rows
//           [K3] MFMA flash attention, O in-place into q-region of qkv
//           [K4] out = O @ bf16(w_proj)^T -> d_out (FP32 stores)
// ---------------------------------------------------------------------------

typedef __attribute__((ext_vector_type(8))) short bf16x8;  // 8 bf16 = 4 VGPRs
typedef __attribute__((ext_vector_type(4))) float f32x4;

#define MFMA16(a, b, c) __builtin_amdgcn_mfma_f32_16x16x32_bf16((a), (b), (c), 0, 0, 0)

#define S_LEN 577
#define NHEAD 12
#define DHEAD 64
#define EMB   768
#define F3    2304   // 3*EMB

// load 8 consecutive fp32, convert to bf16 packed in a uint4 (16B)
__device__ __forceinline__ uint4 load8_f32(const float* p) {
    const float4 f0 = *(const float4*)p;
    const float4 f1 = *(const float4*)(p + 4);
    union { uint4 u; __hip_bfloat16 h[8]; } r;
    r.h[0] = __float2bfloat16(f0.x); r.h[1] = __float2bfloat16(f0.y);
    r.h[2] = __float2bfloat16(f0.z); r.h[3] = __float2bfloat16(f0.w);
    r.h[4] = __float2bfloat16(f1.x); r.h[5] = __float2bfloat16(f1.y);
    r.h[6] = __float2bfloat16(f1.z); r.h[7] = __float2bfloat16(f1.w);
    return r.u;
}

// ---------------------------------------------------------------------------
// K1/K4: C[m][n] = sum_k A[m][k] * B[n][k]
// AF32/BF32: operand is fp32 (converted to bf16 in staging), else bf16.
// CF32: C stored as fp32 (else bf16). A row stride lda; B row stride K.
// N % 128 == 0, K % 32 == 0; M guarded. 128x128 tile, BK=32, 16x16x32 MFMA.
// ---------------------------------------------------------------------------
template<bool AF32, bool BF32, bool CF32>
__global__ __launch_bounds__(256) void gemm_bt_kernel(
    const void* __restrict__ Av, int lda,
    const void* __restrict__ Bv,
    void* __restrict__ Cv,
    int M, int N, int K)
{
    __shared__ __hip_bfloat16 As[128 * 32];   // [row][k], 64B rows
    __shared__ __hip_bfloat16 Bs[128 * 32];

    const int t      = threadIdx.x;
    const int l      = t & 63;
    const int w      = t >> 6;
    const int lane15 = l & 15;
    const int quad   = l >> 4;

    const int n0 = blockIdx.x * 128;
    const int m0 = blockIdx.y * 128;
    const int wm = (w >> 1) * 64;
    const int wn = (w & 1) * 64;

    const int srow   = t >> 2;   // 0..63
    const int schunk = t & 3;    // 0..3  (8 elements = one 16B bf16 chunk)

    int ar0 = m0 + srow;       if (ar0 > M - 1) ar0 = M - 1;
    int ar1 = m0 + 64 + srow;  if (ar1 > M - 1) ar1 = M - 1;
    const int br0 = n0 + srow;
    const int br1 = n0 + 64 + srow;

    const size_t a0off = (size_t)ar0 * lda + schunk * 8;
    const size_t a1off = (size_t)ar1 * lda + schunk * 8;
    const size_t b0off = (size_t)br0 * K + schunk * 8;
    const size_t b1off = (size_t)br1 * K + schunk * 8;

    f32x4 acc[4][4] = {};

    for (int k0 = 0; k0 < K; k0 += 32) {
        uint4 va0, va1, vb0, vb1;
        if constexpr (AF32) {
            va0 = load8_f32((const float*)Av + a0off + k0);
            va1 = load8_f32((const float*)Av + a1off + k0);
        } else {
            va0 = *(const uint4*)((const __hip_bfloat16*)Av + a0off + k0);
            va1 = *(const uint4*)((const __hip_bfloat16*)Av + a1off + k0);
        }
        if constexpr (BF32) {
            vb0 = load8_f32((const float*)Bv + b0off + k0);
            vb1 = load8_f32((const float*)Bv + b1off + k0);
        } else {
            vb0 = *(const uint4*)((const __hip_bfloat16*)Bv + b0off + k0);
            vb1 = *(const uint4*)((const __hip_bfloat16*)Bv + b1off + k0);
        }
        __syncthreads();   // previous iter's frag reads complete
        *(uint4*)(As + srow * 32 + schunk * 8)        = va0;
        *(uint4*)(As + (64 + srow) * 32 + schunk * 8) = va1;
        *(uint4*)(Bs + srow * 32 + schunk * 8)        = vb0;
        *(uint4*)(Bs + (64 + srow) * 32 + schunk * 8) = vb1;
        __syncthreads();

        bf16x8 a[4], b[4];
        #pragma unroll
        for (int i = 0; i < 4; ++i)
            a[i] = *(const bf16x8*)(As + (wm + i * 16 + lane15) * 32 + quad * 8);
        #pragma unroll
        for (int j = 0; j < 4; ++j)
            b[j] = *(const bf16x8*)(Bs + (wn + j * 16 + lane15) * 32 + quad * 8);

        #pragma unroll
        for (int i = 0; i < 4; ++i)
            #pragma unroll
            for (int j = 0; j < 4; ++j)
                acc[i][j] = MFMA16(a[i], b[j], acc[i][j]);
    }

    // epilogue: C/D layout col=lane&15, row=quad*4+reg
    #pragma unroll
    for (int i = 0; i < 4; ++i) {
        #pragma unroll
        for (int r = 0; r < 4; ++r) {
            const int m = m0 + wm + i * 16 + quad * 4 + r;
            if (m < M) {
                #pragma unroll
                for (int j = 0; j < 4; ++j) {
                    const int n = n0 + wn + j * 16 + lane15;
                    if constexpr (CF32)
                        ((float*)Cv)[(size_t)m * N + n] = acc[i][j][r];
                    else
                        ((__hip_bfloat16*)Cv)[(size_t)m * N + n] = __float2bfloat16(acc[i][j][r]);
                }
            }
        }
    }
}

// ---------------------------------------------------------------------------
// K2: RoPE in-place on q and k for patch tokens (s >= 1).
// rx[j] = tx[j]*cos_x[j] + tx[(j-1)%32]*sin_x[j]; cos_x[j] = cos(px[j>>1]);
// px[i] = (p%24)/(23+1e-8) * exp(-(2i) ln(1e4)/32); second half uses y coord.
// ---------------------------------------------------------------------------
__global__ __launch_bounds__(256) void rope_kernel(__hip_bfloat16* __restrict__ qkv)
{
    const int p = blockIdx.x;    // 0..575 patch index
    const int b = blockIdx.y;
    const int l = threadIdx.x & 63;
    const int w = threadIdx.x >> 6;

    const int jj   = l & 31;
    const float i2 = (float)((jj >> 1) * 2);
    const float dv = __expf(-i2 * 0.28782313662425576f);   // ln(10000)/32
    const float inv = 1.0f / (23.0f + 1e-8f);
    const float cx = (float)(p % 24) * inv;   // coords[:,0] = gx = col
    const float cy = (float)(p / 24) * inv;
    const float ang = ((l < 32) ? cx : cy) * dv;
    const float c = __cosf(ang);
    const float s = __sinf(ang);
    const int nb = (l & 32) | ((jj + 31) & 31);   // lane of (j-1)%32, same half

    const size_t rowbase = ((size_t)(b * S_LEN + 1 + p)) * F3;

    for (int pr = w; pr < 24; pr += 4) {
        const int part = pr / 12;    // 0=q, 1=k
        const int h    = pr % 12;
        const size_t off = rowbase + (size_t)part * EMB + h * DHEAD + l;
        float v  = __bfloat162float(qkv[off]);
        float vp = __shfl(v, nb, 64);
        qkv[off] = __float2bfloat16(v * c + vp * s);
    }
}

// ---------------------------------------------------------------------------
// K3: MFMA flash attention. grid (qt=10, h=12, b=32), 256 threads (4 waves).
// Each wave owns 16 q rows; block covers 64 q rows; K/V tiles of 64 keys.
// Q pre-scaled by 0.125. O written with row stride ldo (aliased onto qkv's
// q-region: each block overwrites exactly the q-cells only it reads).
// ---------------------------------------------------------------------------
__global__ __launch_bounds__(256) void attn_kernel(
    const __hip_bfloat16* __restrict__ qkv,
    __hip_bfloat16* __restrict__ attn_out, int ldo)
{
    __shared__ __hip_bfloat16 Qs[64][72];
    __shared__ __hip_bfloat16 Ks[64][72];
    __shared__ __hip_bfloat16 Vt[64][72];      // transposed: Vt[d][s]
    __shared__ __hip_bfloat16 Ps[4][16][72];   // per-wave P round-trip (C->A layout)

    const int t      = threadIdx.x;
    const int l      = t & 63;
    const int w      = t >> 6;
    const int lane15 = l & 15;
    const int quad   = l >> 4;

    const int q0 = blockIdx.x * 64;
    const int h  = blockIdx.y;
    const int b  = blockIdx.z;

    // ---- stage Q (scaled) ----
    {
        const int row = t >> 2, seg = t & 3;
        int gq = q0 + row; if (gq > S_LEN - 1) gq = S_LEN - 1;
        const uint4* src = (const uint4*)(qkv + (size_t)(b * S_LEN + gq) * F3 + h * DHEAD + seg * 16);
        uint4 u0 = src[0], u1 = src[1];
        const __hip_bfloat16* e0 = (const __hip_bfloat16*)&u0;
        const __hip_bfloat16* e1 = (const __hip_bfloat16*)&u1;
        #pragma unroll
        for (int i = 0; i < 8; ++i) {
            Qs[row][seg * 16 + i]     = __float2bfloat16(__bfloat162float(e0[i]) * 0.125f);
            Qs[row][seg * 16 + 8 + i] = __float2bfloat16(__bfloat162float(e1[i]) * 0.125f);
        }
    }
    __syncthreads();

    // A-operand frags for Q: A[m=lane&15][k=quad*8+j]  (held whole loop)
    bf16x8 qf0 = *(const bf16x8*)&Qs[w * 16 + lane15][quad * 8];
    bf16x8 qf1 = *(const bf16x8*)&Qs[w * 16 + lane15][32 + quad * 8];

    f32x4 o[4] = {};                       // O[q=quad*4+r][d=ci*16+lane15]
    float m_i[4] = {-3.0e38f, -3.0e38f, -3.0e38f, -3.0e38f};
    float l_i[4] = {0.f, 0.f, 0.f, 0.f};

    for (int s0 = 0; s0 < S_LEN; s0 += 64) {
        __syncthreads();   // prior tile's Ks/Vt reads complete
        // ---- stage K tile ----
        {
            const int row = t >> 2, seg = t & 3;
            int gk = s0 + row; if (gk > S_LEN - 1) gk = S_LEN - 1;
            const uint4* src = (const uint4*)(qkv + (size_t)(b * S_LEN + gk) * F3 + EMB + h * DHEAD + seg * 16);
            *(uint4*)&Ks[row][seg * 16]     = src[0];
            *(uint4*)&Ks[row][seg * 16 + 8] = src[1];
        }
        // ---- stage V tile, transposed ----
        {
            const int s = t & 63, dg = t >> 6;
            int gk = s0 + s; if (gk > S_LEN - 1) gk = S_LEN - 1;
            const uint4* src = (const uint4*)(qkv + (size_t)(b * S_LEN + gk) * F3 + 2 * EMB + h * DHEAD + dg * 16);
            uint4 u0 = src[0], u1 = src[1];
            const __hip_bfloat16* e0 = (const __hip_bfloat16*)&u0;
            const __hip_bfloat16* e1 = (const __hip_bfloat16*)&u1;
            #pragma unroll
            for (int i = 0; i < 8; ++i) {
                Vt[dg * 16 + i][s]     = e0[i];
                Vt[dg * 16 + 8 + i][s] = e1[i];
            }
        }
        __syncthreads();

        // ---- S = Q K^T (16 q rows x 64 keys per wave) ----
        f32x4 sf[4];
        #pragma unroll
        for (int nt = 0; nt < 4; ++nt) {
            f32x4 z = {0.f, 0.f, 0.f, 0.f};
            bf16x8 k0f = *(const bf16x8*)&Ks[nt * 16 + lane15][quad * 8];
            bf16x8 k1f = *(const bf16x8*)&Ks[nt * 16 + lane15][32 + quad * 8];
            z = MFMA16(qf0, k0f, z);
            z = MFMA16(qf1, k1f, z);
            sf[nt] = z;
        }
        #pragma unroll
        for (int nt = 0; nt < 4; ++nt) {
            if (s0 + nt * 16 + lane15 >= S_LEN)
                sf[nt] = (f32x4){-1e30f, -1e30f, -1e30f, -1e30f};
        }

        // ---- online softmax; rows r=0..3 are q rows quad*4+r ----
        float alpha[4];
        #pragma unroll
        for (int r = 0; r < 4; ++r) {
            float mx = fmaxf(fmaxf(sf[0][r], sf[1][r]), fmaxf(sf[2][r], sf[3][r]));
            #pragma unroll
            for (int off = 1; off < 16; off <<= 1)
                mx = fmaxf(mx, __shfl_xor(mx, off, 64));
            float mnew = fmaxf(m_i[r], mx);
            alpha[r] = __expf(m_i[r] - mnew);
            m_i[r] = mnew;
        }

        float pv[4][4];   // [nt][r]
        #pragma unroll
        for (int nt = 0; nt < 4; ++nt)
            #pragma unroll
            for (int r = 0; r < 4; ++r)
                pv[nt][r] = __expf(sf[nt][r] - m_i[r]);

        #pragma unroll
        for (int r = 0; r < 4; ++r) {
            float sum = pv[0][r] + pv[1][r] + pv[2][r] + pv[3][r];
            #pragma unroll
            for (int off = 1; off < 16; off <<= 1)
                sum += __shfl_xor(sum, off, 64);
            l_i[r] = l_i[r] * alpha[r] + sum;
        }

        #pragma unroll
        for (int ci = 0; ci < 4; ++ci)
            #pragma unroll
            for (int r = 0; r < 4; ++r)
                o[ci][r] *= alpha[r];

        // ---- P: C-layout -> LDS -> A-layout ----
        #pragma unroll
        for (int nt = 0; nt < 4; ++nt)
            #pragma unroll
            for (int r = 0; r < 4; ++r)
                Ps[w][quad * 4 + r][nt * 16 + lane15] = __float2bfloat16(pv[nt][r]);
        __syncthreads();

        // ---- O += P V ----
        #pragma unroll
        for (int s32 = 0; s32 < 2; ++s32) {
            bf16x8 pa = *(const bf16x8*)&Ps[w][lane15][s32 * 32 + quad * 8];
            #pragma unroll
            for (int ci = 0; ci < 4; ++ci) {
                bf16x8 vb = *(const bf16x8*)&Vt[ci * 16 + lane15][s32 * 32 + quad * 8];
                o[ci] = MFMA16(pa, vb, o[ci]);
            }
        }
    }

    // ---- epilogue: O / l_i -> attn_out[(b,q) row, h*64+d] (bf16 ws) ----
    #pragma unroll
    for (int r = 0; r < 4; ++r) {
        const int q = q0 + w * 16 + quad * 4 + r;
        if (q < S_LEN) {
            const float rl = 1.0f / l_i[r];
            #pragma unroll
            for (int ci = 0; ci < 4; ++ci) {
                attn_out[(size_t)(b * S_LEN + q) * ldo + h * DHEAD + ci * 16 + lane15] =
                    __float2bfloat16(o[ci][r] * rl);
            }
        }
    }
}

// ---------------------------------------------------------------------------
extern "C" void kernel_launch(void* const* d_in, const int* in_sizes, int n_in,
                              void* d_out, int out_size, void* d_ws, size_t ws_size,
                              hipStream_t stream) {
    // resolve inputs by flat element count (all sizes distinct)
    const float* x      = (const float*)d_in[0];
    const float* w_qkv  = (const float*)d_in[1];
    const float* w_proj = (const float*)d_in[2];
    for (int i = 0; i < n_in; ++i) {
        if      (in_sizes[i] == 32 * S_LEN * EMB) x      = (const float*)d_in[i];
        else if (in_sizes[i] == F3 * EMB)         w_qkv  = (const float*)d_in[i];
        else if (in_sizes[i] == EMB * EMB)        w_proj = (const float*)d_in[i];
    }
    float* out = (float*)d_out;     // FP32 output (contract + r5 forensics)

    const int Mrows = 32 * S_LEN;   // 18464
    __hip_bfloat16* qkv = (__hip_bfloat16*)d_ws;    // [M][2304] bf16, 81.1 MiB

    // K1: qkv = bf16(x) @ bf16(w_qkv)^T   (fp32 in, bf16 staging, bf16 store)
    gemm_bt_kernel<true, true, false><<<dim3(F3 / 128, (Mrows + 127) / 128), 256, 0, stream>>>(
        x, EMB, w_qkv, qkv, Mrows, F3, EMB);
    // K2: RoPE on q,k patch rows
    rope_kernel<<<dim3(576, 32), 256, 0, stream>>>(qkv);
    // K3: attention; O overwrites q-region of qkv (row stride F3)
    attn_kernel<<<dim3((S_LEN + 63) / 64, NHEAD, 32), 256, 0, stream>>>(qkv, qkv, F3);
    // K4: out = O @ bf16(w_proj)^T -> FP32 stores to d_out
    gemm_bt_kernel<false, true, true><<<dim3(EMB / 128, (Mrows + 127) / 128), 256, 0, stream>>>(
        qkv, F3, w_proj, out, Mrows, EMB, EMB);
}

// Round 7
// 433.551 us; speedup vs baseline: 1.0795x; 1.0795x over previous
//
#include <hip/hip_runtime.h>
#include <hip/hip_bf16.h>
#include <cstdint>

// ---------------------------------------------------------------------------
// RoPE Multi-Head Self-Attention, MI355X (gfx950)
// B=32, S=577, E=768, H=12, Dh=64.  Inputs fp32, output fp32 (r6-verified).
// Internally bf16 MFMA / fp32 accumulate; qkv workspace bf16.
// Round 7:
//  [C1,C2] convert x, w_qkv -> bf16 into d_out-as-scratch (dead until K4)
//  [K1] qkv = xb @ wb^T           (pure-bf16, global_load_lds DMA staging)
//  [K2] RoPE in-place on q,k patch rows
//  [K3] flash attention, 512 thr / 128-row Q tile (staging amortized 2x)
//  [K4] out = O @ bf16(w_proj)^T  (A via DMA, B fp32 register-convert, C fp32)
// ---------------------------------------------------------------------------

typedef __attribute__((ext_vector_type(8))) short bf16x8;  // 8 bf16 = 4 VGPRs
typedef __attribute__((ext_vector_type(4))) float f32x4;

#define MFMA16(a, b, c) __builtin_amdgcn_mfma_f32_16x16x32_bf16((a), (b), (c), 0, 0, 0)

#define S_LEN 577
#define NHEAD 12
#define DHEAD 64
#define EMB   768
#define F3    2304   // 3*EMB

// async global->LDS, 16B/lane; LDS dest must be wave-uniform base + lane*16.
__device__ __forceinline__ void gload_lds16(const __hip_bfloat16* g, __hip_bfloat16* l) {
    __builtin_amdgcn_global_load_lds(
        (const __attribute__((address_space(1))) unsigned int*)g,
        (__attribute__((address_space(3))) unsigned int*)l, 16, 0, 0);
}

// load 8 consecutive fp32, convert to bf16 packed in a uint4 (16B)
__device__ __forceinline__ uint4 load8_f32(const float* p) {
    const float4 f0 = *(const float4*)p;
    const float4 f1 = *(const float4*)(p + 4);
    union { uint4 u; __hip_bfloat16 h[8]; } r;
    r.h[0] = __float2bfloat16(f0.x); r.h[1] = __float2bfloat16(f0.y);
    r.h[2] = __float2bfloat16(f0.z); r.h[3] = __float2bfloat16(f0.w);
    r.h[4] = __float2bfloat16(f1.x); r.h[5] = __float2bfloat16(f1.y);
    r.h[6] = __float2bfloat16(f1.z); r.h[7] = __float2bfloat16(f1.w);
    return r.u;
}

// ---------------------------------------------------------------------------
// C1/C2: fp32 -> bf16 bulk convert (n must be a multiple of 8; ours are)
// ---------------------------------------------------------------------------
__global__ __launch_bounds__(256) void cvt_f32_bf16(
    const float* __restrict__ src, __hip_bfloat16* __restrict__ dst, int n8)
{
    const int i = blockIdx.x * 256 + threadIdx.x;
    if (i < n8)
        *(uint4*)(dst + (size_t)i * 8) = load8_f32(src + (size_t)i * 8);
}

// ---------------------------------------------------------------------------
// K1/K4: C[m][n] = sum_k A[m][k] * B[n][k]
// A: bf16, row stride lda, staged via global_load_lds DMA.
// B: BF32 ? fp32 register-convert staging : bf16 DMA staging. Row stride ldb.
// C: CF32 ? fp32 : bf16.  N%128==0, K%32==0; M guarded.
// 128x128 tile, BK=32, 16x16x32 MFMA, 4 waves x 4x4 acc frags (m97 structure).
// ---------------------------------------------------------------------------
template<bool BF32, bool CF32>
__global__ __launch_bounds__(256) void gemm_a_dma(
    const __hip_bfloat16* __restrict__ A, int lda,
    const void* __restrict__ Bv, int ldb,
    void* __restrict__ Cv, int M, int N, int K)
{
    __shared__ __hip_bfloat16 As[128 * 32];   // [row][k], 64B rows (DMA layout)
    __shared__ __hip_bfloat16 Bs[128 * 32];

    const int t      = threadIdx.x;
    const int l      = t & 63;
    const int w      = t >> 6;
    const int lane15 = l & 15;
    const int quad   = l >> 4;

    const int n0 = blockIdx.x * 128;
    const int m0 = blockIdx.y * 128;
    const int wm = (w >> 1) * 64;
    const int wn = (w & 1) * 64;

    const int srow   = t >> 2;   // 0..63
    const int schunk = t & 3;    // 0..3 (16B chunks)

    int ar0 = m0 + srow;       if (ar0 > M - 1) ar0 = M - 1;
    int ar1 = m0 + 64 + srow;  if (ar1 > M - 1) ar1 = M - 1;
    const int br0 = n0 + srow;
    const int br1 = n0 + 64 + srow;

    const __hip_bfloat16* pa0 = A + (size_t)ar0 * lda + schunk * 8;
    const __hip_bfloat16* pa1 = A + (size_t)ar1 * lda + schunk * 8;
    const size_t b0off = (size_t)br0 * ldb + schunk * 8;
    const size_t b1off = (size_t)br1 * ldb + schunk * 8;

    __hip_bfloat16* lAs0 = As + srow * 32 + schunk * 8;          // == As + t*8
    __hip_bfloat16* lAs1 = As + (64 + srow) * 32 + schunk * 8;
    __hip_bfloat16* lBs0 = Bs + srow * 32 + schunk * 8;
    __hip_bfloat16* lBs1 = Bs + (64 + srow) * 32 + schunk * 8;

    f32x4 acc[4][4] = {};

    for (int k0 = 0; k0 < K; k0 += 32) {
        uint4 vb0, vb1;
        if constexpr (BF32) {   // issue B global loads before barrier (overlap)
            vb0 = load8_f32((const float*)Bv + b0off + k0);
            vb1 = load8_f32((const float*)Bv + b1off + k0);
        }
        __syncthreads();        // prior iter's frag reads complete
        gload_lds16(pa0 + k0, lAs0);
        gload_lds16(pa1 + k0, lAs1);
        if constexpr (BF32) {
            *(uint4*)lBs0 = vb0;
            *(uint4*)lBs1 = vb1;
        } else {
            gload_lds16((const __hip_bfloat16*)Bv + b0off + k0, lBs0);
            gload_lds16((const __hip_bfloat16*)Bv + b1off + k0, lBs1);
        }
        __syncthreads();        // compiler drains vmcnt+lgkmcnt before barrier

        bf16x8 a[4], b[4];
        #pragma unroll
        for (int i = 0; i < 4; ++i)
            a[i] = *(const bf16x8*)(As + (wm + i * 16 + lane15) * 32 + quad * 8);
        #pragma unroll
        for (int j = 0; j < 4; ++j)
            b[j] = *(const bf16x8*)(Bs + (wn + j * 16 + lane15) * 32 + quad * 8);

        #pragma unroll
        for (int i = 0; i < 4; ++i)
            #pragma unroll
            for (int j = 0; j < 4; ++j)
                acc[i][j] = MFMA16(a[i], b[j], acc[i][j]);
    }

    // epilogue: C/D layout col=lane&15, row=quad*4+reg
    #pragma unroll
    for (int i = 0; i < 4; ++i) {
        #pragma unroll
        for (int r = 0; r < 4; ++r) {
            const int m = m0 + wm + i * 16 + quad * 4 + r;
            if (m < M) {
                #pragma unroll
                for (int j = 0; j < 4; ++j) {
                    const int n = n0 + wn + j * 16 + lane15;
                    if constexpr (CF32)
                        ((float*)Cv)[(size_t)m * N + n] = acc[i][j][r];
                    else
                        ((__hip_bfloat16*)Cv)[(size_t)m * N + n] = __float2bfloat16(acc[i][j][r]);
                }
            }
        }
    }
}

// ---------------------------------------------------------------------------
// K2: RoPE in-place on q and k for patch tokens (s >= 1) — r6-verified.
// ---------------------------------------------------------------------------
__global__ __launch_bounds__(256) void rope_kernel(__hip_bfloat16* __restrict__ qkv)
{
    const int p = blockIdx.x;    // 0..575 patch index
    const int b = blockIdx.y;
    const int l = threadIdx.x & 63;
    const int w = threadIdx.x >> 6;

    const int jj   = l & 31;
    const float i2 = (float)((jj >> 1) * 2);
    const float dv = __expf(-i2 * 0.28782313662425576f);   // ln(10000)/32
    const float inv = 1.0f / (23.0f + 1e-8f);
    const float cx = (float)(p % 24) * inv;
    const float cy = (float)(p / 24) * inv;
    const float ang = ((l < 32) ? cx : cy) * dv;
    const float c = __cosf(ang);
    const float s = __sinf(ang);
    const int nb = (l & 32) | ((jj + 31) & 31);   // lane of (j-1)%32, same half

    const size_t rowbase = ((size_t)(b * S_LEN + 1 + p)) * F3;

    for (int pr = w; pr < 24; pr += 4) {
        const int part = pr / 12;    // 0=q, 1=k
        const int h    = pr % 12;
        const size_t off = rowbase + (size_t)part * EMB + h * DHEAD + l;
        float v  = __bfloat162float(qkv[off]);
        float vp = __shfl(v, nb, 64);
        qkv[off] = __float2bfloat16(v * c + vp * s);
    }
}

// ---------------------------------------------------------------------------
// K3: MFMA flash attention, 512 threads (8 waves), Q tile = 128 rows.
// grid (qt=5, h=12, b=32). Wave w owns q rows w*16..w*16+15 of the tile.
// K/V tiles of 64 keys; staging split across 512 threads (2x amortized).
// Q pre-scaled by 0.125. O written with row stride ldo (aliased onto qkv's
// q-region; each block overwrites exactly the q-cells only it reads).
// ---------------------------------------------------------------------------
__global__ __launch_bounds__(512) void attn_kernel(
    const __hip_bfloat16* __restrict__ qkv,
    __hip_bfloat16* __restrict__ attn_out, int ldo)
{
    __shared__ __hip_bfloat16 Qs[128][72];
    __shared__ __hip_bfloat16 Ks[64][72];
    __shared__ __hip_bfloat16 Vt[64][72];      // transposed: Vt[d][s]
    __shared__ __hip_bfloat16 Ps[8][16][72];   // per-wave P round-trip (C->A)

    const int t      = threadIdx.x;
    const int l      = t & 63;
    const int w      = t >> 6;     // 0..7
    const int lane15 = l & 15;
    const int quad   = l >> 4;

    const int q0 = blockIdx.x * 128;
    const int h  = blockIdx.y;
    const int b  = blockIdx.z;

    // ---- stage Q (scaled): row = t>>2 (0..127), seg = t&3 (16 elems) ----
    {
        const int row = t >> 2, seg = t & 3;
        int gq = q0 + row; if (gq > S_LEN - 1) gq = S_LEN - 1;
        const uint4* src = (const uint4*)(qkv + (size_t)(b * S_LEN + gq) * F3 + h * DHEAD + seg * 16);
        uint4 u0 = src[0], u1 = src[1];
        const __hip_bfloat16* e0 = (const __hip_bfloat16*)&u0;
        const __hip_bfloat16* e1 = (const __hip_bfloat16*)&u1;
        #pragma unroll
        for (int i = 0; i < 8; ++i) {
            Qs[row][seg * 16 + i]     = __float2bfloat16(__bfloat162float(e0[i]) * 0.125f);
            Qs[row][seg * 16 + 8 + i] = __float2bfloat16(__bfloat162float(e1[i]) * 0.125f);
        }
    }
    __syncthreads();

    // A-operand frags for Q: A[m=lane&15][k=quad*8+j]  (held whole loop)
    bf16x8 qf0 = *(const bf16x8*)&Qs[w * 16 + lane15][quad * 8];
    bf16x8 qf1 = *(const bf16x8*)&Qs[w * 16 + lane15][32 + quad * 8];

    f32x4 o[4] = {};                       // O[q=quad*4+r][d=ci*16+lane15]
    float m_i[4] = {-3.0e38f, -3.0e38f, -3.0e38f, -3.0e38f};
    float l_i[4] = {0.f, 0.f, 0.f, 0.f};

    for (int s0 = 0; s0 < S_LEN; s0 += 64) {
        __syncthreads();   // prior tile's Ks/Vt/Ps reads complete
        // ---- stage K tile: row = t>>3 (0..63), seg8 = t&7 (8 elems) ----
        {
            const int row = t >> 3, seg8 = t & 7;
            int gk = s0 + row; if (gk > S_LEN - 1) gk = S_LEN - 1;
            const uint4* src = (const uint4*)(qkv + (size_t)(b * S_LEN + gk) * F3 + EMB + h * DHEAD);
            *(uint4*)&Ks[row][seg8 * 8] = src[seg8];
        }
        // ---- stage V tile transposed: s = t&63, dg = t>>6 (8 dims) ----
        {
            const int s = t & 63, dg = t >> 6;
            int gk = s0 + s; if (gk > S_LEN - 1) gk = S_LEN - 1;
            const uint4* src = (const uint4*)(qkv + (size_t)(b * S_LEN + gk) * F3 + 2 * EMB + h * DHEAD);
            uint4 u0 = src[dg];
            const __hip_bfloat16* e0 = (const __hip_bfloat16*)&u0;
            #pragma unroll
            for (int i = 0; i < 8; ++i)
                Vt[dg * 8 + i][s] = e0[i];
        }
        __syncthreads();

        // ---- S = Q K^T (16 q rows x 64 keys per wave) ----
        f32x4 sf[4];
        #pragma unroll
        for (int nt = 0; nt < 4; ++nt) {
            f32x4 z = {0.f, 0.f, 0.f, 0.f};
            bf16x8 k0f = *(const bf16x8*)&Ks[nt * 16 + lane15][quad * 8];
            bf16x8 k1f = *(const bf16x8*)&Ks[nt * 16 + lane15][32 + quad * 8];
            z = MFMA16(qf0, k0f, z);
            z = MFMA16(qf1, k1f, z);
            sf[nt] = z;
        }
        #pragma unroll
        for (int nt = 0; nt < 4; ++nt) {
            if (s0 + nt * 16 + lane15 >= S_LEN)
                sf[nt] = (f32x4){-1e30f, -1e30f, -1e30f, -1e30f};
        }

        // ---- online softmax; rows r=0..3 are q rows quad*4+r ----
        float alpha[4];
        #pragma unroll
        for (int r = 0; r < 4; ++r) {
            float mx = fmaxf(fmaxf(sf[0][r], sf[1][r]), fmaxf(sf[2][r], sf[3][r]));
            #pragma unroll
            for (int off = 1; off < 16; off <<= 1)
                mx = fmaxf(mx, __shfl_xor(mx, off, 64));
            float mnew = fmaxf(m_i[r], mx);
            alpha[r] = __expf(m_i[r] - mnew);
            m_i[r] = mnew;
        }

        float pv[4][4];   // [nt][r]
        #pragma unroll
        for (int nt = 0; nt < 4; ++nt)
            #pragma unroll
            for (int r = 0; r < 4; ++r)
                pv[nt][r] = __expf(sf[nt][r] - m_i[r]);

        #pragma unroll
        for (int r = 0; r < 4; ++r) {
            float sum = pv[0][r] + pv[1][r] + pv[2][r] + pv[3][r];
            #pragma unroll
            for (int off = 1; off < 16; off <<= 1)
                sum += __shfl_xor(sum, off, 64);
            l_i[r] = l_i[r] * alpha[r] + sum;
        }

        #pragma unroll
        for (int ci = 0; ci < 4; ++ci)
            #pragma unroll
            for (int r = 0; r < 4; ++r)
                o[ci][r] *= alpha[r];

        // ---- P: C-layout -> LDS -> A-layout (wave-local; no block barrier,
        //      just drain own LDS writes — r4/r5 proved same-wave safety) ----
        #pragma unroll
        for (int nt = 0; nt < 4; ++nt)
            #pragma unroll
            for (int r = 0; r < 4; ++r)
                Ps[w][quad * 4 + r][nt * 16 + lane15] = __float2bfloat16(pv[nt][r]);
        asm volatile("s_waitcnt lgkmcnt(0)" ::: "memory");

        // ---- O += P V ----
        #pragma unroll
        for (int s32 = 0; s32 < 2; ++s32) {
            bf16x8 pa = *(const bf16x8*)&Ps[w][lane15][s32 * 32 + quad * 8];
            #pragma unroll
            for (int ci = 0; ci < 4; ++ci) {
                bf16x8 vb = *(const bf16x8*)&Vt[ci * 16 + lane15][s32 * 32 + quad * 8];
                o[ci] = MFMA16(pa, vb, o[ci]);
            }
        }
    }

    // ---- epilogue: O / l_i -> attn_out[(b,q) row, h*64+d] (bf16 ws) ----
    #pragma unroll
    for (int r = 0; r < 4; ++r) {
        const int q = q0 + w * 16 + quad * 4 + r;
        if (q < S_LEN) {
            const float rl = 1.0f / l_i[r];
            #pragma unroll
            for (int ci = 0; ci < 4; ++ci) {
                attn_out[(size_t)(b * S_LEN + q) * ldo + h * DHEAD + ci * 16 + lane15] =
                    __float2bfloat16(o[ci][r] * rl);
            }
        }
    }
}

// ---------------------------------------------------------------------------
extern "C" void kernel_launch(void* const* d_in, const int* in_sizes, int n_in,
                              void* d_out, int out_size, void* d_ws, size_t ws_size,
                              hipStream_t stream) {
    const float* x      = (const float*)d_in[0];
    const float* w_qkv  = (const float*)d_in[1];
    const float* w_proj = (const float*)d_in[2];
    for (int i = 0; i < n_in; ++i) {
        if      (in_sizes[i] == 32 * S_LEN * EMB) x      = (const float*)d_in[i];
        else if (in_sizes[i] == F3 * EMB)         w_qkv  = (const float*)d_in[i];
        else if (in_sizes[i] == EMB * EMB)        w_proj = (const float*)d_in[i];
    }
    float* out = (float*)d_out;     // fp32 output (r6-verified)

    const int Mrows = 32 * S_LEN;           // 18464
    const int NX    = Mrows * EMB;          // 14,180,352 (mult of 8)
    const int NWQ   = F3 * EMB;             // 1,769,472  (mult of 8)

    __hip_bfloat16* qkv = (__hip_bfloat16*)d_ws;        // [M][2304] bf16, 81.1 MiB
    // d_out as scratch until K4 overwrites it: xb (28.4 MB) + wb (3.4 MB) < 56.7 MB
    __hip_bfloat16* xb  = (__hip_bfloat16*)d_out;
    __hip_bfloat16* wb  = xb + (size_t)NX;

    // C1/C2: fp32 -> bf16 converts into d_out scratch
    cvt_f32_bf16<<<NX / 8 / 256, 256, 0, stream>>>(x, xb, NX / 8);
    cvt_f32_bf16<<<NWQ / 8 / 256, 256, 0, stream>>>(w_qkv, wb, NWQ / 8);
    // K1: qkv = xb @ wb^T  (pure-bf16 DMA staging, bf16 C)
    gemm_a_dma<false, false><<<dim3(F3 / 128, (Mrows + 127) / 128), 256, 0, stream>>>(
        xb, EMB, wb, EMB, qkv, Mrows, F3, EMB);
    // K2: RoPE on q,k patch rows
    rope_kernel<<<dim3(576, 32), 256, 0, stream>>>(qkv);
    // K3: attention (512 thr, 128-row Q tiles); O overwrites q-region of qkv
    attn_kernel<<<dim3((S_LEN + 127) / 128, NHEAD, 32), 512, 0, stream>>>(qkv, qkv, F3);
    // K4: out = O @ bf16(w_proj)^T  (A DMA bf16 stride F3; B fp32 convert; C fp32)
    gemm_a_dma<true, true><<<dim3(EMB / 128, (Mrows + 127) / 128), 256, 0, stream>>>(
        qkv, F3, w_proj, EMB, out, Mrows, EMB, EMB);
}